// Round 8
// baseline (299.897 us; speedup 1.0000x reference)
//
#include <hip/hip_runtime.h>

#define N 8192
#define M 8192
#define D 256
#define LOG2E 1.44269504088896340736f

typedef unsigned short ushort_t;
typedef __attribute__((ext_vector_type(8))) short short8;
typedef __attribute__((ext_vector_type(4))) float floatx4;

__device__ __forceinline__ unsigned short f2bf(float f) {
  unsigned int u = __float_as_uint(f);
  u += 0x7fffu + ((u >> 16) & 1u);   // round-to-nearest-even
  return (unsigned short)(u >> 16);
}

// prep writes xb/sb as 1KB MFMA-FRAGMENT TILES (layout HW-verified R4/R6):
//   row r, elem k -> byte  g*32768 + (c*4 + sub)*1024 + q*256 + m*16 + b*2
//   g = r>>6, sub = (r>>4)&3, m = r&15, c = k>>5, q = (k>>3)&3, b = k&7
// Within each 1KB tile, byte l*16 is exactly lane l's 16x16x32 bf16 fragment
// slice. Staging = contiguous 1KB global_load_lds (linear dest, m104);
// fragment ds_read_b128 = wave-uniform base + lane*16 (zero conflicts).
//
// Norms are stored PRE-FOLDED for the epilogue: xn'' = -(log2e/D)*||x||^2,
// so the epilogue is exp2(fma(2*log2e/D, acc, xn''+sn'')) -- 4 VALU/trans ops
// per element instead of ~7 (epilogue arithmetic modeled at ~24 us chip-time).
__global__ __launch_bounds__(256) void prep_kernel(const float* __restrict__ x,
                                                   const float* __restrict__ s,
                                                   ushort_t* __restrict__ xb,
                                                   ushort_t* __restrict__ sb,
                                                   float* __restrict__ xn,
                                                   float* __restrict__ sn) {
  int gw = blockIdx.x * 4 + (threadIdx.x >> 6);
  int lane = threadIdx.x & 63;
  const float* src;
  ushort_t* dst;
  float* nrm;
  int row;
  if (gw < N) { src = x; dst = xb; nrm = xn; row = gw; }
  else        { src = s; dst = sb; nrm = sn; row = gw - N; }
  float4 v = ((const float4*)(src + (size_t)row * D))[lane];  // k = 4*lane..+3
  float ss = v.x * v.x + v.y * v.y + v.z * v.z + v.w * v.w;
  ushort4 o;
  o.x = f2bf(v.x); o.y = f2bf(v.y); o.z = f2bf(v.z); o.w = f2bf(v.w);
  const int g = row >> 6;
  const int sub = (row >> 4) & 3;
  const int m = row & 15;
  const int c = lane >> 3;        // k-chunk of this lane's 4 elems
  const int q = (lane >> 1) & 3;  // k-quarter within chunk
  size_t off = (size_t)g * 32768 +
               (size_t)((c * 4 + sub) * 1024 + q * 256 + m * 16 + (lane & 1) * 8);
  *(ushort4*)((char*)dst + off) = o;
#pragma unroll
  for (int offs = 32; offs > 0; offs >>= 1) ss += __shfl_down(ss, offs);
  if (lane == 0) nrm[row] = ss * (-LOG2E / (float)D);
}

// Stage one BK=64 round t into one buffer pair: per wave 4 A-tiles + 4 B-tiles
// (1 KB each). Tile tt = g*8 + c32*4 + sub  (g: 64-row group, c32: 32-k chunk
// of this round, sub: 16-row panel) -- same index in global image and LDS.
__device__ __forceinline__ void stage_round(const char* gX, const char* gS,
                                            ushort_t* lA, ushort_t* lB,
                                            int t, int wave, int lane) {
#pragma unroll
  for (int i = 0; i < 4; ++i) {
    const int tt = wave * 4 + i;
    const int g = tt >> 3, c32 = (tt >> 2) & 1, sub = tt & 3;
    const size_t goff = (size_t)g * 32768 +
                        (size_t)(((2 * t + c32) * 4 + sub) * 1024) + lane * 16;
    __builtin_amdgcn_global_load_lds(
        (const __attribute__((address_space(1))) void*)(gX + goff),
        (__attribute__((address_space(3))) void*)((char*)lA + tt * 1024), 16, 0, 0);
    __builtin_amdgcn_global_load_lds(
        (const __attribute__((address_space(1))) void*)(gS + goff),
        (__attribute__((address_space(3))) void*)((char*)lB + tt * 1024), 16, 0, 0);
  }
}

// Compute one BK=64 round from one buffer pair: 16 lane-linear ds_read_b128 +
// 32 MFMA per wave.
__device__ __forceinline__ void compute_round(const ushort_t* __restrict__ As_,
                                              const ushort_t* __restrict__ Bs_,
                                              floatx4 (&acc)[4][4], int wave,
                                              int lane) {
  const int pa = (wave >> 1) * 4;  // a 16-row-panel base (0..7)
  const int pb = (wave & 1) * 4;   // b panel base
#pragma unroll
  for (int c32 = 0; c32 < 2; ++c32) {
    short8 a_frag[4], b_frag[4];
#pragma unroll
    for (int i = 0; i < 4; ++i) {
      const int p = pa + i;
      a_frag[i] = *(const short8*)((const char*)As_ +
                  (((p >> 2) * 8 + c32 * 4 + (p & 3)) * 1024) + lane * 16);
    }
#pragma unroll
    for (int j = 0; j < 4; ++j) {
      const int p = pb + j;
      b_frag[j] = *(const short8*)((const char*)Bs_ +
                  (((p >> 2) * 8 + c32 * 4 + (p & 3)) * 1024) + lane * 16);
    }
#pragma unroll
    for (int i = 0; i < 4; ++i)
#pragma unroll
      for (int j = 0; j < 4; ++j)
        acc[i][j] = __builtin_amdgcn_mfma_f32_16x16x32_bf16(a_frag[i], b_frag[j],
                                                            acc[i][j], 0, 0, 0);
  }
}

// 128x128 C-tile, 4 waves (2x2). Guide SS5.5 T3 "minimum 2-phase" rotation
// (m248v2, refcheck'd, plain HIP): BK=64, double-buffered 2x32KB = 64 KB ->
// 2 blocks/CU. Per round: issue stage(t+1) into the other buffer BEFORE the
// ds_reads+MFMAs of round t; one __syncthreads() per round (its compiler-
// emitted vmcnt(0)+barrier IS the recipe's "vmcnt(0); barrier") -- the load
// flight hides under the round's compute instead of being fully exposed as in
// the R0/R6 stage-then-drain order. No inline asm (R1/R2 lesson, m141).
__global__ __launch_bounds__(256, 2) void rbf_gemm(const ushort_t* __restrict__ X,
                                                   const ushort_t* __restrict__ S,
                                                   const float* __restrict__ xn,
                                                   const float* __restrict__ sn,
                                                   float* __restrict__ out) {
  __shared__ __attribute__((aligned(16))) ushort_t As[2][8192];  // 2 x 16 KB
  __shared__ __attribute__((aligned(16))) ushort_t Bs[2][8192];  // 2 x 16 KB

  const int tid = threadIdx.x;
  const int lane = tid & 63;
  const int wave = tid >> 6;
  const int bx = blockIdx.x;  // col block (support)
  const int by = blockIdx.y;  // row block (x)

  const char* gX = (const char*)X + (size_t)by * 65536;  // 2 row-groups
  const char* gS = (const char*)S + (size_t)bx * 65536;

  floatx4 acc[4][4];
#pragma unroll
  for (int i = 0; i < 4; ++i)
#pragma unroll
    for (int j = 0; j < 4; ++j) acc[i][j] = (floatx4){0.f, 0.f, 0.f, 0.f};

  stage_round(gX, gS, As[0], Bs[0], 0, wave, lane);
  __syncthreads();  // drain stage(0)

#pragma unroll
  for (int t = 0; t < 4; ++t) {
    if (t < 3)  // prefetch next round into the other buffer (flight overlaps
      stage_round(gX, gS, As[(t + 1) & 1], Bs[(t + 1) & 1], t + 1, wave, lane);
    compute_round(As[t & 1], Bs[t & 1], acc, wave, lane);
    if (t < 3)
      __syncthreads();  // vmcnt(0)+barrier: stage(t+1) ready, buf(t) released
  }

  // Epilogue. C/D layout (m89/m91): col = lane&15, row = (lane>>4)*4 + reg.
  // arg = xn'' + sn'' + (2*log2e/D)*acc  (<= 0 after clamp); out = 2^arg via
  // v_exp_f32 (__builtin_amdgcn_exp2f -- HIP has no __exp2f device function).
  // Norms read directly from global (L2-hot 32KB arrays): 4 float4 + 4 scalar
  // per thread -- no norm LDS, no per-element ds_reads.
  const int wr = (wave >> 1) * 64;
  const int wc = (wave & 1) * 64;
  const int q4 = lane >> 4;
  const int m16 = lane & 15;

  floatx4 rowA[4];
  const float* xrow = xn + by * 128 + wr + q4 * 4;
#pragma unroll
  for (int i = 0; i < 4; ++i) rowA[i] = *(const floatx4*)(xrow + i * 16);
  float colB[4];
#pragma unroll
  for (int j = 0; j < 4; ++j) colB[j] = sn[bx * 128 + wc + j * 16 + m16];

  const float k2 = 2.0f * LOG2E / (float)D;
#pragma unroll
  for (int i = 0; i < 4; ++i) {
#pragma unroll
    for (int j = 0; j < 4; ++j) {
#pragma unroll
      for (int r = 0; r < 4; ++r) {
        const int rl = wr + i * 16 + q4 * 4 + r;
        const int cl = wc + j * 16 + m16;
        float arg = fminf(fmaf(k2, acc[i][j][r], rowA[i][r] + colB[j]), 0.0f);
        out[(size_t)(by * 128 + rl) * M + (bx * 128 + cl)] =
            __builtin_amdgcn_exp2f(arg);
      }
    }
  }
}

extern "C" void kernel_launch(void* const* d_in, const int* in_sizes, int n_in,
                              void* d_out, int out_size, void* d_ws, size_t ws_size,
                              hipStream_t stream) {
  const float* x = (const float*)d_in[0];
  const float* s = (const float*)d_in[1];
  float* out = (float*)d_out;
  char* ws = (char*)d_ws;
  ushort_t* xb = (ushort_t*)ws;                           // 4 MB bf16 X (frag-tiled)
  ushort_t* sb = (ushort_t*)(ws + (size_t)N * D * 2);     // 4 MB bf16 S (frag-tiled)
  float* xn = (float*)(ws + (size_t)(N + M) * D * 2);     // 32 KB (pre-folded)
  float* sn = xn + N;                                     // 32 KB (pre-folded)

  prep_kernel<<<(N + M) / 4, 256, 0, stream>>>(x, s, xb, sb, xn, sn);
  dim3 grid(M / 128, N / 128);
  rbf_gemm<<<grid, 256, 0, stream>>>(xb, sb, xn, sn, out);
}